// Round 6
// baseline (209.095 us; speedup 1.0000x reference)
//
#include <hip/hip_runtime.h>

#define B_    256
#define G_    200
#define S_    100
#define NODE_ 200
#define E_    128
#define H_    8
#define M_    300
#define MT_   19     // m tiles of 16 (304 padded)
#define NT_   13     // n/g tiles of 16 (208 padded)

typedef float    f32x4 __attribute__((ext_vector_type(4)));
typedef short    s16x4 __attribute__((ext_vector_type(4)));
typedef short    s16x8 __attribute__((ext_vector_type(8)));
typedef unsigned u32x4 __attribute__((ext_vector_type(4)));

#define MFMA16(A, B, C) __builtin_amdgcn_mfma_f32_16x16x32_bf16(A, B, C, 0, 0, 0)

#define LOG2E_  1.4426950408889634f
#define CQ_     0.36067376022224085f   // 0.25 * log2e
#define C2T_    0.25503901628148863f   // 2 * (1/sqrt(128)) * log2e
#define C10L_   14.426950408889634f    // 10 * log2e

// ---- split-bf16 helpers ----
__device__ __forceinline__ unsigned bf16u(float x) {
    unsigned u = __builtin_bit_cast(unsigned, x);
    return (u + 0x7fffu + ((u >> 16) & 1u)) >> 16;
}
__device__ __forceinline__ float bfbits(unsigned hb16) {
    return __builtin_bit_cast(float, hb16 << 16);
}
__device__ __forceinline__ short bfhi(float x) { return (short)bf16u(x); }
__device__ __forceinline__ short bflo(float x, short hi) {
    float hf = __builtin_bit_cast(float, ((unsigned)(unsigned short)hi) << 16);
    return (short)bf16u(x - hf);
}
__device__ __forceinline__ unsigned cvtpk(float a, float b) {
    unsigned r;
    asm("v_cvt_pk_bf16_f32 %0, %1, %2" : "=v"(r) : "v"(a), "v"(b));
    return r;
}
__device__ __forceinline__ float exp2a(float x) {   // 2^x via v_exp_f32
    float r;
    asm("v_exp_f32 %0, %1" : "=v"(r) : "v"(x));
    return r;
}
__device__ __forceinline__ s16x8 cat8(s16x4 a, s16x4 b) {
    s16x8 r; r[0]=a[0]; r[1]=a[1]; r[2]=a[2]; r[3]=a[3];
             r[4]=b[0]; r[5]=b[1]; r[6]=b[2]; r[7]=b[3]; return r;
}
// pack f32x4 -> two interleaved B-fragments {hi,lo} and {lo,hi}
__device__ __forceinline__ void split_pack(f32x4 v, s16x8& B1, s16x8& B2) {
    unsigned h01 = cvtpk(v[0], v[1]);
    unsigned h23 = cvtpk(v[2], v[3]);
    float e0 = v[0] - __builtin_bit_cast(float, h01 << 16);
    float e1 = v[1] - __builtin_bit_cast(float, h01 & 0xffff0000u);
    float e2 = v[2] - __builtin_bit_cast(float, h23 << 16);
    float e3 = v[3] - __builtin_bit_cast(float, h23 & 0xffff0000u);
    unsigned l01 = cvtpk(e0, e1), l23 = cvtpk(e2, e3);
    u32x4 w1 = {h01, h23, l01, l23};
    u32x4 w2 = {l01, l23, h01, h23};
    B1 = __builtin_bit_cast(s16x8, w1);
    B2 = __builtin_bit_cast(s16x8, w2);
}
// pack two f32x4 (K-halves) -> full-K {hi} and {lo} B-fragments
__device__ __forceinline__ void pack8(f32x4 a0, f32x4 a1, s16x8& Bh, s16x8& Bl) {
    unsigned ha = cvtpk(a0[0], a0[1]), hb = cvtpk(a0[2], a0[3]);
    unsigned hc = cvtpk(a1[0], a1[1]), hd = cvtpk(a1[2], a1[3]);
    float e0 = a0[0] - __builtin_bit_cast(float, ha << 16);
    float e1 = a0[1] - __builtin_bit_cast(float, ha & 0xffff0000u);
    float e2 = a0[2] - __builtin_bit_cast(float, hb << 16);
    float e3 = a0[3] - __builtin_bit_cast(float, hb & 0xffff0000u);
    float e4 = a1[0] - __builtin_bit_cast(float, hc << 16);
    float e5 = a1[1] - __builtin_bit_cast(float, hc & 0xffff0000u);
    float e6 = a1[2] - __builtin_bit_cast(float, hd << 16);
    float e7 = a1[3] - __builtin_bit_cast(float, hd & 0xffff0000u);
    unsigned la = cvtpk(e0, e1), lb = cvtpk(e2, e3);
    unsigned lc = cvtpk(e4, e5), ld = cvtpk(e6, e7);
    u32x4 wh = {ha, hb, hc, hd}, wl = {la, lb, lc, ld};
    Bh = __builtin_bit_cast(s16x8, wh);
    Bl = __builtin_bit_cast(s16x8, wl);
}

// =================== setup: W fragments ===================
__global__ __launch_bounds__(64) void wfrag_kernel(
    const float* __restrict__ Wk, const float* __restrict__ Wv,
    const float* __restrict__ Wl, const float* __restrict__ Wc,
    short* __restrict__ wf8_hi, short* __restrict__ wf8_lo)
{
    const int p = blockIdx.x, ct = blockIdx.y;
    const int l = threadIdx.x, qq = l >> 4, li = l & 15;
    const float* W = (p == 0) ? Wk : ((p == 1) ? Wv : ((p == 2) ? Wl : Wc));
    for (int kc = 0; kc < 8; ++kc) {
        s16x4 hi, lo;
        #pragma unroll
        for (int j = 0; j < 4; ++j) {
            float v = W[(kc*16 + qq*4 + j)*E_ + ct*16 + li];
            short h = bfhi(v); hi[j] = h; lo[j] = bflo(v, h);
        }
        const int ix = (((p*8 + ct)*4 + (kc >> 1))*64 + l)*8 + (kc & 1)*4;
        *(s16x4*)(wf8_hi + ix) = hi;
        *(s16x4*)(wf8_lo + ix) = lo;
    }
}

// =================== qbase[b][c] = graph[b] @ Wq[:128] ===================
__global__ __launch_bounds__(128) void qbase_kernel(
    const float* __restrict__ graph, const float* __restrict__ Wq,
    float* __restrict__ qbase)
{
    const int b = blockIdx.x, c = threadIdx.x;
    __shared__ float gs[E_];
    gs[c] = graph[b*E_ + c];
    __syncthreads();
    float acc = 0.f;
    #pragma unroll 8
    for (int e = 0; e < E_; ++e) acc += gs[e] * Wq[e*E_ + c];
    qbase[b*E_ + c] = acc;
}

// =================== proj: k/v/shk fragments ===================
__global__ __launch_bounds__(64, 4) void proj_kernel(
    const float* __restrict__ enc,
    const short* __restrict__ wf8_hi, const short* __restrict__ wf8_lo,
    short* __restrict__ kf_il, short* __restrict__ vf_il,
    short* __restrict__ sf8_hi, short* __restrict__ sf8_lo)
{
    int id = blockIdx.x;
    { const int xcd = id & 7, pos = id >> 3; id = xcd*608 + pos; }
    const int b = id / MT_, mt = id % MT_;
    const int l = threadIdx.x, qq = l >> 4, li = l & 15;
    const int m = mt*16 + li;

    s16x8 Ahi[4], Alo[4];
    #pragma unroll
    for (int u = 0; u < 4; ++u) {
        float va[8];
        if (m < M_) {
            const float* ep = enc + ((size_t)b*M_ + m)*E_ + u*32 + qq*4;
            float4 f0 = *(const float4*)ep;
            float4 f1 = *(const float4*)(ep + 16);
            va[0]=f0.x; va[1]=f0.y; va[2]=f0.z; va[3]=f0.w;
            va[4]=f1.x; va[5]=f1.y; va[6]=f1.z; va[7]=f1.w;
        } else {
            #pragma unroll
            for (int j = 0; j < 8; ++j) va[j] = 0.f;
        }
        #pragma unroll
        for (int j = 0; j < 8; ++j) {
            short h = bfhi(va[j]); Ahi[u][j] = h; Alo[u][j] = bflo(va[j], h);
        }
    }

    __shared__ unsigned tile[16*17];

    #pragma unroll
    for (int p = 0; p < 3; ++p) {
        if (p == 2 && mt >= NT_) break;
        #pragma unroll
        for (int ct = 0; ct < 8; ++ct) {
            f32x4 acc = {0.f, 0.f, 0.f, 0.f};
            #pragma unroll
            for (int u = 0; u < 4; ++u) {
                const int base = (((p*8 + ct)*4 + u)*64 + l)*8;
                s16x8 Bh = *(const s16x8*)(wf8_hi + base);
                s16x8 Bl = *(const s16x8*)(wf8_lo + base);
                acc = MFMA16(Ahi[u], Bh, acc);
                acc = MFMA16(Ahi[u], Bl, acc);
                acc = MFMA16(Alo[u], Bh, acc);
            }
            if (p == 1) {
                s16x4 oh, ol;
                #pragma unroll
                for (int r = 0; r < 4; ++r) { short h = bfhi(acc[r]); oh[r] = h; ol[r] = bflo(acc[r], h); }
                const size_t ix = (((size_t)(b*8 + ct))*MT_ + mt)*512 + (size_t)l*8;
                *(s16x8*)(vf_il + ix) = cat8(oh, ol);
            } else {
                #pragma unroll
                for (int r = 0; r < 4; ++r) {
                    short h = bfhi(acc[r]); short lo = bflo(acc[r], h);
                    tile[(qq*4 + r)*17 + li] = (((unsigned)(unsigned short)h) << 16) | (unsigned short)(unsigned)lo;
                }
                __syncthreads();
                s16x4 oh, ol;
                #pragma unroll
                for (int j = 0; j < 4; ++j) {
                    unsigned wv = tile[li*17 + qq*4 + j];
                    oh[j] = (short)(wv >> 16); ol[j] = (short)(wv & 0xffffu);
                }
                if (p == 0) {
                    const size_t ix = (((size_t)(b*8 + ct))*MT_ + mt)*512 + (size_t)l*8;
                    *(s16x8*)(kf_il + ix) = cat8(oh, ol);
                } else {
                    const size_t ix = (((size_t)(b*NT_ + mt))*4 + (ct >> 1))*512 + (size_t)l*8 + (ct & 1)*4;
                    *(s16x4*)(sf8_hi + ix) = oh;
                    *(s16x4*)(sf8_lo + ix) = ol;
                }
                __syncthreads();
            }
        }
    }
}

// =================== attn1: scores + no-max softmax + PV -> outws ===================
__global__ __launch_bounds__(256, 3) void attn1_kernel(
    const float* __restrict__ capacity, const float* __restrict__ sols_mask,
    const float* __restrict__ ninf_mask, const float* __restrict__ Wq,
    const float* __restrict__ qbase,
    const short* __restrict__ kf_il, const short* __restrict__ vf_il,
    float* __restrict__ outws)
{
    int id = blockIdx.x;                       // 3328 = 8*416
    { const int xcd = id & 7, pos = id >> 3; id = xcd*416 + pos; }
    const int b = id / NT_, gt = id % NT_;
    const int t = threadIdx.x;
    const int w = t >> 6, l = t & 63, qq = l >> 4, li = l & 15;
    const int g0 = gt*16;

    __shared__ unsigned mlds[MT_][64][2];      // 9728 B: masks pre-scaled by log2e

    // ---- coalesced mask fill, pre-scaled by log2e ----
    {
        const size_t bg = (size_t)b*G_;
        for (int f = t; f < 1600; f += 256) {          // ninf: 16 rows x 100 float2
            const int g = f/100, p = f - g*100;
            int gg = g0 + g; gg = (gg < G_) ? gg : G_-1;
            float2 v = *(const float2*)(ninf_mask + (bg + gg)*NODE_ + p*2);
            const int mm = p*2;
            mlds[mm>>4][((mm>>2)&3)*16 + g][(mm>>1)&1] = cvtpk(v.x*LOG2E_, v.y*LOG2E_);
        }
        for (int f = t; f < 800; f += 256) {           // sols: 16 rows x 50 float2
            const int g = f/50, p = f - g*50;
            int gg = g0 + g; gg = (gg < G_) ? gg : G_-1;
            float2 v = *(const float2*)(sols_mask + (bg + gg)*S_ + p*2);
            const int mm = 200 + p*2;
            mlds[mm>>4][((mm>>2)&3)*16 + g][(mm>>1)&1] = cvtpk(v.x*LOG2E_, v.y*LOG2E_);
        }
        if (t < 32) {                                  // pad rows m=300..303 -> -inf
            mlds[18][48 + (t>>1)][t&1] = 0xFF80FF80u;
        }
    }
    __syncthreads();

    int ggl = g0 + li; ggl = (ggl < G_) ? ggl : G_-1;
    const float cap = capacity[b*G_ + ggl];
    const bool isN12 = (qq < 2);               // tile 12 rows m=192..199 are nodes iff qq<2

    #pragma unroll 1
    for (int hi2 = 0; hi2 < 2; ++hi2) {
        const int h = w*2 + hi2;
        // ---- q interleaved B-frags ----
        s16x8 qB1, qB2;
        {
            float4 qb4 = *(const float4*)(qbase + b*E_ + h*16 + qq*4);
            float4 wl4 = *(const float4*)(Wq + E_*E_ + h*16 + qq*4);
            f32x4 qv = {qb4.x + cap*wl4.x, qb4.y + cap*wl4.y,
                        qb4.z + cap*wl4.z, qb4.w + cap*wl4.w};
            split_pack(qv, qB1, qB2);
        }
        // ---- scoresT[m][g] ----
        f32x4 sc[MT_];
        const size_t kb = ((size_t)(b*8 + h)*MT_)*512 + (size_t)l*8;
        #pragma unroll
        for (int mt = 0; mt < MT_; ++mt) {
            s16x8 kf8 = *(const s16x8*)(kf_il + kb + (size_t)mt*512);
            f32x4 a = {0.f, 0.f, 0.f, 0.f};
            a = MFMA16(kf8, qB1, a);
            a = MFMA16(kf8, qB2, a);
            sc[mt] = a;
        }
        // ---- no-max softmax: e = exp2(s*CQ + mask*log2e); segmented sums ----
        f32x4 sA = {0.f,0.f,0.f,0.f}, sB = {0.f,0.f,0.f,0.f}, sC = {0.f,0.f,0.f,0.f};
        #pragma unroll
        for (int mt = 0; mt < MT_; ++mt) {
            const uint2 mp = *(const uint2*)&mlds[mt][l][0];
            f32x4 e;
            e[0] = exp2a(fmaf(sc[mt][0], CQ_, bfbits(mp.x & 0xffffu)));
            e[1] = exp2a(fmaf(sc[mt][1], CQ_, bfbits(mp.x >> 16)));
            e[2] = exp2a(fmaf(sc[mt][2], CQ_, bfbits(mp.y & 0xffffu)));
            e[3] = exp2a(fmaf(sc[mt][3], CQ_, bfbits(mp.y >> 16)));
            sc[mt] = e;
            if (mt < 12)       { if (mt & 1) sB += e; else sA += e; }
            else if (mt > 12)  sC += e;
        }
        float s12 = (sc[12][0] + sc[12][1]) + (sc[12][2] + sc[12][3]);
        f32x4 sAB = sA + sB;
        float sN = (sAB[0] + sAB[1]) + (sAB[2] + sAB[3]) + (isN12 ? s12 : 0.f);
        float sS = (sC[0] + sC[1]) + (sC[2] + sC[3]) + (isN12 ? 0.f : s12);
        sN += __shfl_xor(sN, 16); sN += __shfl_xor(sN, 32);
        sS += __shfl_xor(sS, 16); sS += __shfl_xor(sS, 32);
        const float rN = 1.f / sN, rS = 1.f / sS;
        { const float r12 = isN12 ? rN : rS; sc[12] *= r12; }   // tile 12 pre-normalized

        // ---- PV with deferred normalization (segmented accumulators) ----
        f32x4 oN0 = {0.f,0.f,0.f,0.f}, oN1 = {0.f,0.f,0.f,0.f};
        f32x4 oS0 = {0.f,0.f,0.f,0.f}, oS1 = {0.f,0.f,0.f,0.f};
        f32x4 o12 = {0.f,0.f,0.f,0.f};
        #pragma unroll
        for (int mt = 0; mt < MT_; ++mt) {
            s16x8 pB1, pB2;
            split_pack(sc[mt], pB1, pB2);
            s16x8 vf8 = *(const s16x8*)(vf_il + kb + (size_t)mt*512);
            f32x4& acc = (mt < 12) ? ((mt & 1) ? oN1 : oN0)
                       : (mt == 12 ? o12 : ((mt & 1) ? oS1 : oS0));
            acc = MFMA16(vf8, pB1, acc);
            acc = MFMA16(vf8, pB2, acc);
        }
        f32x4 on = oN0 + oN1, os = oS0 + oS1, osum;
        #pragma unroll
        for (int r = 0; r < 4; ++r)
            osum[r] = fmaf(on[r], rN, fmaf(os[r], rS, o12[r]));

        *(f32x4*)(outws + (((size_t)(b*NT_ + gt))*8 + h)*256 + (size_t)l*4) = osum;
    }
}

// =================== attn2: Wc + final logits GEMM + tanh + no-max softmax ===================
__global__ __launch_bounds__(64, 4) void attn2_kernel(
    const float* __restrict__ ninf_mask,
    const short* __restrict__ sf8_hi, const short* __restrict__ sf8_lo,
    const short* __restrict__ wf8_hi, const short* __restrict__ wf8_lo,
    const float* __restrict__ bc_,
    const float* __restrict__ outws,
    float* __restrict__ out)
{
    int id = blockIdx.x;
    { const int xcd = id & 7, pos = id >> 3; id = xcd*416 + pos; }
    const int b = id / NT_, gt = id % NT_;
    const int l = threadIdx.x, qq = l >> 4, li = l & 15;
    const int g0 = gt*16;

    __shared__ float pool[16*308];

    {
        const size_t bg = (size_t)b*G_;
        for (int f = l; f < 800; f += 64) {
            const int g = f/50, p = f - g*50;
            int gg = g0 + g; gg = (gg < G_) ? gg : G_-1;
            *(float4*)&pool[g*308 + p*4] = *(const float4*)(ninf_mask + (bg + gg)*NODE_ + p*4);
        }
    }
    __syncthreads();

    s16x8 BhO[4], BlO[4];
    #pragma unroll
    for (int u = 0; u < 4; ++u) {
        f32x4 a0 = *(const f32x4*)(outws + (((size_t)(b*NT_ + gt))*8 + 2*u)*256 + (size_t)l*4);
        f32x4 a1 = *(const f32x4*)(outws + (((size_t)(b*NT_ + gt))*8 + 2*u + 1)*256 + (size_t)l*4);
        pack8(a0, a1, BhO[u], BlO[u]);
    }
    s16x8 Bh2[4], Bl2[4];
    #pragma unroll
    for (int u = 0; u < 4; ++u) {
        f32x4 t01[2];
        #pragma unroll
        for (int half = 0; half < 2; ++half) {
            const int jt = 2*u + half;
            f32x4 acc = {0.f, 0.f, 0.f, 0.f};
            #pragma unroll
            for (int uu = 0; uu < 4; ++uu) {
                const int base = (((3*8 + jt)*4 + uu)*64 + l)*8;
                s16x8 Ah = *(const s16x8*)(wf8_hi + base);
                s16x8 Al = *(const s16x8*)(wf8_lo + base);
                acc = MFMA16(Ah, BhO[uu], acc);
                acc = MFMA16(Ah, BlO[uu], acc);
                acc = MFMA16(Al, BhO[uu], acc);
            }
            float4 b4 = *(const float4*)(bc_ + jt*16 + qq*4);
            acc[0] += b4.x; acc[1] += b4.y; acc[2] += b4.z; acc[3] += b4.w;
            t01[half] = acc;
        }
        pack8(t01[0], t01[1], Bh2[u], Bl2[u]);
    }
    f32x4 z[NT_];
    #pragma unroll
    for (int nt = 0; nt < NT_; ++nt) {
        f32x4 acc = {0.f, 0.f, 0.f, 0.f};
        #pragma unroll
        for (int u = 0; u < 4; ++u) {
            const size_t base = (((size_t)(b*NT_ + nt))*4 + u)*512 + (size_t)l*8;
            s16x8 Ah = *(const s16x8*)(sf8_hi + base);
            s16x8 Al = *(const s16x8*)(sf8_lo + base);
            acc = MFMA16(Ah, Bh2[u], acc);
            acc = MFMA16(Ah, Bl2[u], acc);
            acc = MFMA16(Al, Bh2[u], acc);
        }
        z[nt] = acc;
    }
    // ---- no-max final softmax in exp2 domain: w = exp2(10*tanh(z*rE)*log2e + mask*log2e) ----
    float sm = 0.f;
    #pragma unroll
    for (int nt = 0; nt < NT_; ++nt) {
        f32x4 mk = *(const f32x4*)&pool[li*308 + nt*16 + qq*4];
        f32x4 e;
        #pragma unroll
        for (int r = 0; r < 4; ++r) {
            if (nt < 12 || (qq*4 + r) < 8) {
                float ex = exp2a(z[nt][r] * C2T_);
                float th = 1.f - 2.f / (ex + 1.f);
                e[r] = exp2a(fmaf(th, C10L_, mk[r]*LOG2E_));
            } else e[r] = 0.f;
        }
        z[nt] = e;
        sm += (e[0] + e[1]) + (e[2] + e[3]);
    }
    sm += __shfl_xor(sm, 16); sm += __shfl_xor(sm, 32);
    const float rs = 1.f / sm;

    float* ob = out + (size_t)b*G_*NODE_;
    __syncthreads();
    #pragma unroll
    for (int ch = 0; ch < 4; ++ch) {
        const int ntn = (ch < 3) ? 4 : 1;
        for (int k = 0; k < ntn; ++k) {
            const int nt = ch*4 + k;
            #pragma unroll
            for (int r = 0; r < 4; ++r)
                pool[li*69 + k*16 + qq*4 + r] = z[nt][r] * rs;
        }
        __syncthreads();
        const int n = ch*64 + l;
        const bool nok = (ch < 3) || (l < 8);
        #pragma unroll
        for (int gi = 0; gi < 16; ++gi) {
            const int g = g0 + gi;
            if (nok && g < G_) ob[(size_t)g*NODE_ + n] = pool[gi*69 + l];
        }
        __syncthreads();
    }
}

// =================== launch ===================
extern "C" void kernel_launch(void* const* d_in, const int* in_sizes, int n_in,
                              void* d_out, int out_size, void* d_ws, size_t ws_size,
                              hipStream_t stream) {
    (void)in_sizes; (void)n_in; (void)out_size; (void)ws_size;
    const float* graph = (const float*)d_in[0];
    const float* capacity = (const float*)d_in[1];
    const float* sols_mask = (const float*)d_in[2];
    const float* ninf_mask = (const float*)d_in[3];
    const float* enc = (const float*)d_in[4];
    const float* Wq  = (const float*)d_in[5];
    const float* Wk  = (const float*)d_in[6];
    const float* Wv  = (const float*)d_in[7];
    const float* Wc  = (const float*)d_in[8];
    const float* bc  = (const float*)d_in[9];
    const float* Wkl = (const float*)d_in[10];
    float* out = (float*)d_out;

    // ws layout (bytes), total 94,765,056 (R4-proven)
    char* wsb = (char*)d_ws;
    short* kf_il  = (short*)(wsb);                   // 39,845,888
    short* sf8_hi = (short*)(wsb + 39845888);        // 13,631,488
    short* sf8_lo = (short*)(wsb + 53477376);        // 13,631,488
    short* wf8_hi = (short*)(wsb + 67108864);        //    131,072
    short* wf8_lo = (short*)(wsb + 67239936);        //    131,072
    float* qb     = (float*)(wsb + 67371008);        //    131,072
    float* outws  = (float*)(wsb + 67502080);        // 27,262,976 -> 94,765,056
    // v fragments live in d_out (dead before attn2 overwrites it): 39.8MB <= 40.96MB
    short* vf_il  = (short*)d_out;

    wfrag_kernel<<<dim3(4, 8), 64, 0, stream>>>(Wk, Wv, Wkl, Wc, wf8_hi, wf8_lo);
    qbase_kernel<<<B_, 128, 0, stream>>>(graph, Wq, qb);
    proj_kernel<<<MT_*B_, 64, 0, stream>>>(enc, wf8_hi, wf8_lo, kf_il, vf_il, sf8_hi, sf8_lo);
    attn1_kernel<<<NT_*B_, 256, 0, stream>>>(capacity, sols_mask, ninf_mask, Wq, qb,
                                             kf_il, vf_il, outws);
    attn2_kernel<<<NT_*B_, 64, 0, stream>>>(ninf_mask, sf8_hi, sf8_lo, wf8_hi, wf8_lo,
                                            bc, outws, out);
}

// Round 8
// 173.928 us; speedup vs baseline: 1.2022x; 1.2022x over previous
//
#include <hip/hip_runtime.h>

#define B_    256
#define G_    200
#define S_    100
#define NODE_ 200
#define E_    128
#define H_    8
#define M_    300
#define MT_   19     // m tiles of 16 (304 padded)
#define NT_   13     // n/g tiles of 16 (208 padded)

typedef float    f32x4 __attribute__((ext_vector_type(4)));
typedef short    s16x4 __attribute__((ext_vector_type(4)));
typedef short    s16x8 __attribute__((ext_vector_type(8)));
typedef unsigned u32x4 __attribute__((ext_vector_type(4)));

#define MFMA16(A, B, C) __builtin_amdgcn_mfma_f32_16x16x32_bf16(A, B, C, 0, 0, 0)

#define LOG2E_  1.4426950408889634f
#define CQ_     0.36067376022224085f   // 0.25 * log2e
#define C2T_    0.25503901628148863f   // 2 * (1/sqrt(128)) * log2e
#define C10L_   14.426950408889634f    // 10 * log2e

#if defined(__has_builtin)
#  if __has_builtin(__builtin_amdgcn_exp2f)
#    define EXP2_BUILTIN 1
#  endif
#endif

__device__ __forceinline__ float exp2a(float x) {
#ifdef EXP2_BUILTIN
    return __builtin_amdgcn_exp2f(x);
#else
    float r;
    asm("v_exp_f32 %0, %1" : "=v"(r) : "v"(x));
    return r;
#endif
}

// ---- split-bf16 helpers ----
__device__ __forceinline__ unsigned bf16u(float x) {
    unsigned u = __builtin_bit_cast(unsigned, x);
    return (u + 0x7fffu + ((u >> 16) & 1u)) >> 16;
}
__device__ __forceinline__ float bfbits(unsigned hb16) {
    return __builtin_bit_cast(float, hb16 << 16);
}
__device__ __forceinline__ short bfhi(float x) { return (short)bf16u(x); }
__device__ __forceinline__ short bflo(float x, short hi) {
    float hf = __builtin_bit_cast(float, ((unsigned)(unsigned short)hi) << 16);
    return (short)bf16u(x - hf);
}
__device__ __forceinline__ unsigned cvtpk(float a, float b) {
    unsigned r;
    asm("v_cvt_pk_bf16_f32 %0, %1, %2" : "=v"(r) : "v"(a), "v"(b));
    return r;
}
__device__ __forceinline__ s16x8 cat8(s16x4 a, s16x4 b) {
    s16x8 r; r[0]=a[0]; r[1]=a[1]; r[2]=a[2]; r[3]=a[3];
             r[4]=b[0]; r[5]=b[1]; r[6]=b[2]; r[7]=b[3]; return r;
}
// pack f32x4 -> two interleaved B-fragments {hi,lo} and {lo,hi}
__device__ __forceinline__ void split_pack(f32x4 v, s16x8& B1, s16x8& B2) {
    unsigned h01 = cvtpk(v[0], v[1]);
    unsigned h23 = cvtpk(v[2], v[3]);
    float e0 = v[0] - __builtin_bit_cast(float, h01 << 16);
    float e1 = v[1] - __builtin_bit_cast(float, h01 & 0xffff0000u);
    float e2 = v[2] - __builtin_bit_cast(float, h23 << 16);
    float e3 = v[3] - __builtin_bit_cast(float, h23 & 0xffff0000u);
    unsigned l01 = cvtpk(e0, e1), l23 = cvtpk(e2, e3);
    u32x4 w1 = {h01, h23, l01, l23};
    u32x4 w2 = {l01, l23, h01, h23};
    B1 = __builtin_bit_cast(s16x8, w1);
    B2 = __builtin_bit_cast(s16x8, w2);
}
// pack two f32x4 (K-halves) -> full-K {hi} and {lo} B-fragments
__device__ __forceinline__ void pack8(f32x4 a0, f32x4 a1, s16x8& Bh, s16x8& Bl) {
    unsigned ha = cvtpk(a0[0], a0[1]), hb = cvtpk(a0[2], a0[3]);
    unsigned hc = cvtpk(a1[0], a1[1]), hd = cvtpk(a1[2], a1[3]);
    float e0 = a0[0] - __builtin_bit_cast(float, ha << 16);
    float e1 = a0[1] - __builtin_bit_cast(float, ha & 0xffff0000u);
    float e2 = a0[2] - __builtin_bit_cast(float, hb << 16);
    float e3 = a0[3] - __builtin_bit_cast(float, hb & 0xffff0000u);
    float e4 = a1[0] - __builtin_bit_cast(float, hc << 16);
    float e5 = a1[1] - __builtin_bit_cast(float, hc & 0xffff0000u);
    float e6 = a1[2] - __builtin_bit_cast(float, hd << 16);
    float e7 = a1[3] - __builtin_bit_cast(float, hd & 0xffff0000u);
    unsigned la = cvtpk(e0, e1), lb = cvtpk(e2, e3);
    unsigned lc = cvtpk(e4, e5), ld = cvtpk(e6, e7);
    u32x4 wh = {ha, hb, hc, hd}, wl = {la, lb, lc, ld};
    Bh = __builtin_bit_cast(s16x8, wh);
    Bl = __builtin_bit_cast(s16x8, wl);
}

// =================== setup: W fragments ===================
__global__ __launch_bounds__(64) void wfrag_kernel(
    const float* __restrict__ Wk, const float* __restrict__ Wv,
    const float* __restrict__ Wl, const float* __restrict__ Wc,
    short* __restrict__ wf8_hi, short* __restrict__ wf8_lo)
{
    const int p = blockIdx.x, ct = blockIdx.y;
    const int l = threadIdx.x, qq = l >> 4, li = l & 15;
    const float* W = (p == 0) ? Wk : ((p == 1) ? Wv : ((p == 2) ? Wl : Wc));
    for (int kc = 0; kc < 8; ++kc) {
        s16x4 hi, lo;
        #pragma unroll
        for (int j = 0; j < 4; ++j) {
            float v = W[(kc*16 + qq*4 + j)*E_ + ct*16 + li];
            short h = bfhi(v); hi[j] = h; lo[j] = bflo(v, h);
        }
        const int ix = (((p*8 + ct)*4 + (kc >> 1))*64 + l)*8 + (kc & 1)*4;
        *(s16x4*)(wf8_hi + ix) = hi;
        *(s16x4*)(wf8_lo + ix) = lo;
    }
}

// =================== qbase[b][c] = graph[b] @ Wq[:128] ===================
__global__ __launch_bounds__(128) void qbase_kernel(
    const float* __restrict__ graph, const float* __restrict__ Wq,
    float* __restrict__ qbase)
{
    const int b = blockIdx.x, c = threadIdx.x;
    __shared__ float gs[E_];
    gs[c] = graph[b*E_ + c];
    __syncthreads();
    float acc = 0.f;
    #pragma unroll 8
    for (int e = 0; e < E_; ++e) acc += gs[e] * Wq[e*E_ + c];
    qbase[b*E_ + c] = acc;
}

// =================== proj: k/v/shk fragments ===================
__global__ __launch_bounds__(64, 4) void proj_kernel(
    const float* __restrict__ enc,
    const short* __restrict__ wf8_hi, const short* __restrict__ wf8_lo,
    short* __restrict__ kf_il, short* __restrict__ vf_il,
    short* __restrict__ sf8_hi, short* __restrict__ sf8_lo)
{
    int id = blockIdx.x;
    { const int xcd = id & 7, pos = id >> 3; id = xcd*608 + pos; }
    const int b = id / MT_, mt = id % MT_;
    const int l = threadIdx.x, qq = l >> 4, li = l & 15;
    const int m = mt*16 + li;

    s16x8 Ahi[4], Alo[4];
    #pragma unroll
    for (int u = 0; u < 4; ++u) {
        float va[8];
        if (m < M_) {
            const float* ep = enc + ((size_t)b*M_ + m)*E_ + u*32 + qq*4;
            float4 f0 = *(const float4*)ep;
            float4 f1 = *(const float4*)(ep + 16);
            va[0]=f0.x; va[1]=f0.y; va[2]=f0.z; va[3]=f0.w;
            va[4]=f1.x; va[5]=f1.y; va[6]=f1.z; va[7]=f1.w;
        } else {
            #pragma unroll
            for (int j = 0; j < 8; ++j) va[j] = 0.f;
        }
        #pragma unroll
        for (int j = 0; j < 8; ++j) {
            short h = bfhi(va[j]); Ahi[u][j] = h; Alo[u][j] = bflo(va[j], h);
        }
    }

    __shared__ unsigned tile[16*17];

    #pragma unroll
    for (int p = 0; p < 3; ++p) {
        if (p == 2 && mt >= NT_) break;
        #pragma unroll
        for (int ct = 0; ct < 8; ++ct) {
            f32x4 acc = {0.f, 0.f, 0.f, 0.f};
            #pragma unroll
            for (int u = 0; u < 4; ++u) {
                const int base = (((p*8 + ct)*4 + u)*64 + l)*8;
                s16x8 Bh = *(const s16x8*)(wf8_hi + base);
                s16x8 Bl = *(const s16x8*)(wf8_lo + base);
                acc = MFMA16(Ahi[u], Bh, acc);
                acc = MFMA16(Ahi[u], Bl, acc);
                acc = MFMA16(Alo[u], Bh, acc);
            }
            if (p == 1) {
                s16x4 oh, ol;
                #pragma unroll
                for (int r = 0; r < 4; ++r) { short h = bfhi(acc[r]); oh[r] = h; ol[r] = bflo(acc[r], h); }
                const size_t ix = (((size_t)(b*8 + ct))*MT_ + mt)*512 + (size_t)l*8;
                *(s16x8*)(vf_il + ix) = cat8(oh, ol);
            } else {
                #pragma unroll
                for (int r = 0; r < 4; ++r) {
                    short h = bfhi(acc[r]); short lo = bflo(acc[r], h);
                    tile[(qq*4 + r)*17 + li] = (((unsigned)(unsigned short)h) << 16) | (unsigned short)(unsigned)lo;
                }
                __syncthreads();
                s16x4 oh, ol;
                #pragma unroll
                for (int j = 0; j < 4; ++j) {
                    unsigned wv = tile[li*17 + qq*4 + j];
                    oh[j] = (short)(wv >> 16); ol[j] = (short)(wv & 0xffffu);
                }
                if (p == 0) {
                    const size_t ix = (((size_t)(b*8 + ct))*MT_ + mt)*512 + (size_t)l*8;
                    *(s16x8*)(kf_il + ix) = cat8(oh, ol);
                } else {
                    const size_t ix = (((size_t)(b*NT_ + mt))*4 + (ct >> 1))*512 + (size_t)l*8 + (ct & 1)*4;
                    *(s16x4*)(sf8_hi + ix) = oh;
                    *(s16x4*)(sf8_lo + ix) = ol;
                }
                __syncthreads();
            }
        }
    }
}

// =================== attn1: streaming scores+exp+PV, deferred norm (tile-12 split) ===================
__global__ __launch_bounds__(256, 6) void attn1_kernel(
    const float* __restrict__ capacity, const float* __restrict__ sols_mask,
    const float* __restrict__ ninf_mask, const float* __restrict__ Wq,
    const float* __restrict__ qbase,
    const short* __restrict__ kf_il, const short* __restrict__ vf_il,
    float* __restrict__ outws)
{
    int id = blockIdx.x;                       // 3328 = 8*416
    { const int xcd = id & 7, pos = id >> 3; id = xcd*416 + pos; }
    const int b = id / NT_, gt = id % NT_;
    const int t = threadIdx.x;
    const int w = t >> 6, l = t & 63, qq = l >> 4, li = l & 15;
    const int g0 = gt*16;

    __shared__ unsigned mlds[MT_][64][2];      // 9728 B: masks pre-scaled by log2e

    // ---- coalesced mask fill, pre-scaled by log2e ----
    {
        const size_t bg = (size_t)b*G_;
        for (int f = t; f < 1600; f += 256) {          // ninf: 16 rows x 100 float2
            const int g = f/100, p = f - g*100;
            int gg = g0 + g; gg = (gg < G_) ? gg : G_-1;
            float2 v = *(const float2*)(ninf_mask + (bg + gg)*NODE_ + p*2);
            const int mm = p*2;
            mlds[mm>>4][((mm>>2)&3)*16 + g][(mm>>1)&1] = cvtpk(v.x*LOG2E_, v.y*LOG2E_);
        }
        for (int f = t; f < 800; f += 256) {           // sols: 16 rows x 50 float2
            const int g = f/50, p = f - g*50;
            int gg = g0 + g; gg = (gg < G_) ? gg : G_-1;
            float2 v = *(const float2*)(sols_mask + (bg + gg)*S_ + p*2);
            const int mm = 200 + p*2;
            mlds[mm>>4][((mm>>2)&3)*16 + g][(mm>>1)&1] = cvtpk(v.x*LOG2E_, v.y*LOG2E_);
        }
        if (t < 32) {                                  // pad rows m=300..303 -> -inf
            mlds[18][48 + (t>>1)][t&1] = 0xFF80FF80u;
        }
    }
    __syncthreads();

    int ggl = g0 + li; ggl = (ggl < G_) ? ggl : G_-1;
    const float cap = capacity[b*G_ + ggl];
    const bool isN12 = (qq < 2);               // tile 12 rows m=192..199 are nodes iff qq<2

    #pragma unroll 1
    for (int hi2 = 0; hi2 < 2; ++hi2) {
        const int h = w*2 + hi2;
        // ---- q interleaved B-frags ----
        s16x8 qB1, qB2;
        {
            float4 qb4 = *(const float4*)(qbase + b*E_ + h*16 + qq*4);
            float4 wl4 = *(const float4*)(Wq + E_*E_ + h*16 + qq*4);
            f32x4 qv = {qb4.x + cap*wl4.x, qb4.y + cap*wl4.y,
                        qb4.z + cap*wl4.z, qb4.w + cap*wl4.w};
            split_pack(qv, qB1, qB2);
        }
        const short* kfb = kf_il + ((size_t)(b*8 + h)*MT_)*512 + (size_t)l*8;
        const short* vfb = vf_il + ((size_t)(b*8 + h)*MT_)*512 + (size_t)l*8;

        f32x4 oN0 = {0.f,0.f,0.f,0.f}, oN1 = {0.f,0.f,0.f,0.f};
        f32x4 oS0 = {0.f,0.f,0.f,0.f}, oS1 = {0.f,0.f,0.f,0.f};
        f32x4 vsN = {0.f,0.f,0.f,0.f}, vsS = {0.f,0.f,0.f,0.f};
        float s12 = 0.f;
        const f32x4 zz = {0.f,0.f,0.f,0.f};

        // ---- streaming: 9 pairs + 1 tail; no PV dependency on the sums ----
        #pragma unroll
        for (int gp = 0; gp < 10; ++gp) {
            const int mA = 2*gp, mB = 2*gp + 1;
            s16x8 kfA = *(const s16x8*)(kfb + (size_t)mA*512);
            s16x8 vfA = *(const s16x8*)(vfb + (size_t)mA*512);
            s16x8 kfB = {0,0,0,0,0,0,0,0}, vfB = {0,0,0,0,0,0,0,0};
            if (gp < 9) {
                kfB = *(const s16x8*)(kfb + (size_t)mB*512);
                vfB = *(const s16x8*)(vfb + (size_t)mB*512);
            }
            f32x4 sa = MFMA16(kfA, qB1, zz); sa = MFMA16(kfA, qB2, sa);
            f32x4 sb = zz;
            if (gp < 9) { sb = MFMA16(kfB, qB1, zz); sb = MFMA16(kfB, qB2, sb); }

            const uint2 mpa = *(const uint2*)&mlds[mA][l][0];
            f32x4 ea;
            ea[0] = exp2a(fmaf(sa[0], CQ_, bfbits(mpa.x & 0xffffu)));
            ea[1] = exp2a(fmaf(sa[1], CQ_, bfbits(mpa.x >> 16)));
            ea[2] = exp2a(fmaf(sa[2], CQ_, bfbits(mpa.y & 0xffffu)));
            ea[3] = exp2a(fmaf(sa[3], CQ_, bfbits(mpa.y >> 16)));
            if (mA == 12) {
                // tile 12 straddles node/sol: each lane's 4 rows are entirely one
                // segment (qq<2 -> nodes). Split per-lane and accumulate into the
                // segment accumulators so rN/rS fold correctly AFTER the MFMA.
                s12 = (ea[0] + ea[1]) + (ea[2] + ea[3]);
                f32x4 eN, eS;
                #pragma unroll
                for (int r = 0; r < 4; ++r) {
                    eN[r] = isN12 ? ea[r] : 0.f;
                    eS[r] = isN12 ? 0.f : ea[r];
                }
                s16x8 pN1, pN2, pS1, pS2;
                split_pack(eN, pN1, pN2);
                split_pack(eS, pS1, pS2);
                oN0 = MFMA16(vfA, pN1, oN0); oN0 = MFMA16(vfA, pN2, oN0);
                oS0 = MFMA16(vfA, pS1, oS0); oS0 = MFMA16(vfA, pS2, oS0);
            } else {
                if (mA < 12) vsN += ea; else vsS += ea;
                s16x8 pA1, pA2;
                split_pack(ea, pA1, pA2);
                f32x4& acc = (mA < 12) ? oN0 : oS0;    // even tiles -> chain 0
                acc = MFMA16(vfA, pA1, acc);
                acc = MFMA16(vfA, pA2, acc);
            }
            if (gp < 9) {
                const uint2 mpb = *(const uint2*)&mlds[mB][l][0];
                f32x4 eb;
                eb[0] = exp2a(fmaf(sb[0], CQ_, bfbits(mpb.x & 0xffffu)));
                eb[1] = exp2a(fmaf(sb[1], CQ_, bfbits(mpb.x >> 16)));
                eb[2] = exp2a(fmaf(sb[2], CQ_, bfbits(mpb.y & 0xffffu)));
                eb[3] = exp2a(fmaf(sb[3], CQ_, bfbits(mpb.y >> 16)));
                if (mB < 12) vsN += eb; else vsS += eb;     // mB is never 12
                s16x8 pB1, pB2;
                split_pack(eb, pB1, pB2);
                f32x4& acc2 = (mB < 12) ? oN1 : oS1;   // odd tiles -> chain 1
                acc2 = MFMA16(vfB, pB1, acc2);
                acc2 = MFMA16(vfB, pB2, acc2);
            }
        }
        // ---- cross-lane segment sums; fold all 1/denoms at the very end ----
        float sN = (vsN[0] + vsN[1]) + (vsN[2] + vsN[3]) + (isN12 ? s12 : 0.f);
        float sS = (vsS[0] + vsS[1]) + (vsS[2] + vsS[3]) + (isN12 ? 0.f : s12);
        sN += __shfl_xor(sN, 16); sN += __shfl_xor(sN, 32);
        sS += __shfl_xor(sS, 16); sS += __shfl_xor(sS, 32);
        const float rN = 1.f / sN, rS = 1.f / sS;
        f32x4 on = oN0 + oN1, os = oS0 + oS1, osum;
        #pragma unroll
        for (int r = 0; r < 4; ++r)
            osum[r] = fmaf(on[r], rN, os[r]*rS);

        *(f32x4*)(outws + (((size_t)(b*NT_ + gt))*8 + h)*256 + (size_t)l*4) = osum;
    }
}

// =================== attn2: Wc + final logits GEMM + tanh + no-max softmax ===================
__global__ __launch_bounds__(64, 4) void attn2_kernel(
    const float* __restrict__ ninf_mask,
    const short* __restrict__ sf8_hi, const short* __restrict__ sf8_lo,
    const short* __restrict__ wf8_hi, const short* __restrict__ wf8_lo,
    const float* __restrict__ bc_,
    const float* __restrict__ outws,
    float* __restrict__ out)
{
    int id = blockIdx.x;
    { const int xcd = id & 7, pos = id >> 3; id = xcd*416 + pos; }
    const int b = id / NT_, gt = id % NT_;
    const int l = threadIdx.x, qq = l >> 4, li = l & 15;
    const int g0 = gt*16;

    __shared__ unsigned mpool[16*104];         // 6656 B: bf16-packed pre-scaled ninf; reused as transpose buf

    // ---- coalesced ninf staging (rows g0..g0+15, clamped), packed bf16 x log2e ----
    {
        const size_t bg = (size_t)b*G_;
        for (int f = l; f < 1600; f += 64) {
            const int g = f/100, p = f - g*100;
            int gg = g0 + g; gg = (gg < G_) ? gg : G_-1;
            float2 v = *(const float2*)(ninf_mask + (bg + gg)*NODE_ + p*2);
            mpool[g*104 + p] = cvtpk(v.x*LOG2E_, v.y*LOG2E_);
        }
    }
    __syncthreads();

    s16x8 BhO[4], BlO[4];
    #pragma unroll
    for (int u = 0; u < 4; ++u) {
        f32x4 a0 = *(const f32x4*)(outws + (((size_t)(b*NT_ + gt))*8 + 2*u)*256 + (size_t)l*4);
        f32x4 a1 = *(const f32x4*)(outws + (((size_t)(b*NT_ + gt))*8 + 2*u + 1)*256 + (size_t)l*4);
        pack8(a0, a1, BhO[u], BlO[u]);
    }
    s16x8 Bh2[4], Bl2[4];
    #pragma unroll
    for (int u = 0; u < 4; ++u) {
        f32x4 t01[2];
        #pragma unroll
        for (int half = 0; half < 2; ++half) {
            const int jt = 2*u + half;
            f32x4 acc = {0.f, 0.f, 0.f, 0.f};
            #pragma unroll
            for (int uu = 0; uu < 4; ++uu) {
                const int base = (((3*8 + jt)*4 + uu)*64 + l)*8;
                s16x8 Ah = *(const s16x8*)(wf8_hi + base);
                s16x8 Al = *(const s16x8*)(wf8_lo + base);
                acc = MFMA16(Ah, BhO[uu], acc);
                acc = MFMA16(Ah, BlO[uu], acc);
                acc = MFMA16(Al, BhO[uu], acc);
            }
            float4 b4 = *(const float4*)(bc_ + jt*16 + qq*4);
            acc[0] += b4.x; acc[1] += b4.y; acc[2] += b4.z; acc[3] += b4.w;
            t01[half] = acc;
        }
        pack8(t01[0], t01[1], Bh2[u], Bl2[u]);
    }
    f32x4 z[NT_];
    #pragma unroll
    for (int nt = 0; nt < NT_; ++nt) {
        f32x4 acc = {0.f, 0.f, 0.f, 0.f};
        #pragma unroll
        for (int u = 0; u < 4; ++u) {
            const size_t base = (((size_t)(b*NT_ + nt))*4 + u)*512 + (size_t)l*8;
            s16x8 Ah = *(const s16x8*)(sf8_hi + base);
            s16x8 Al = *(const s16x8*)(sf8_lo + base);
            acc = MFMA16(Ah, Bh2[u], acc);
            acc = MFMA16(Ah, Bl2[u], acc);
            acc = MFMA16(Al, Bh2[u], acc);
        }
        z[nt] = acc;
    }
    // ---- no-max final softmax: w = exp2(10*log2e*tanh(z*rE) + mask_pre) ----
    float sm = 0.f;
    #pragma unroll
    for (int nt = 0; nt < NT_; ++nt) {
        const uint2 mp = *(const uint2*)&mpool[li*104 + ((nt*8 + qq*2 < 100) ? nt*8 + qq*2 : 0)];
        f32x4 e;
        #pragma unroll
        for (int r = 0; r < 4; ++r) {
            if (nt < 12 || (qq*4 + r) < 8) {
                float ex = exp2a(z[nt][r] * C2T_);
                float th = 1.f - 2.f / (ex + 1.f);
                const unsigned mb = (r == 0) ? (mp.x & 0xffffu) : (r == 1) ? (mp.x >> 16)
                                  : (r == 2) ? (mp.y & 0xffffu) : (mp.y >> 16);
                e[r] = exp2a(fmaf(th, C10L_, bfbits(mb)));
            } else e[r] = 0.f;
        }
        z[nt] = e;
        sm += (e[0] + e[1]) + (e[2] + e[3]);
    }
    sm += __shfl_xor(sm, 16); sm += __shfl_xor(sm, 32);
    const float rs = 1.f / sm;

    // ---- transpose via LDS (mpool reused as float buf, stride 69), coalesced stores ----
    float* tbuf = (float*)mpool;
    float* ob = out + (size_t)b*G_*NODE_;
    __syncthreads();
    #pragma unroll
    for (int ch = 0; ch < 4; ++ch) {
        const int ntn = (ch < 3) ? 4 : 1;
        for (int k = 0; k < ntn; ++k) {
            const int nt = ch*4 + k;
            #pragma unroll
            for (int r = 0; r < 4; ++r)
                tbuf[li*69 + k*16 + qq*4 + r] = z[nt][r] * rs;
        }
        __syncthreads();
        const int n = ch*64 + l;
        const bool nok = (ch < 3) || (l < 8);
        #pragma unroll
        for (int gi = 0; gi < 16; ++gi) {
            const int g = g0 + gi;
            if (nok && g < G_) ob[(size_t)g*NODE_ + n] = tbuf[gi*69 + l];
        }
        __syncthreads();
    }
}

// =================== launch ===================
extern "C" void kernel_launch(void* const* d_in, const int* in_sizes, int n_in,
                              void* d_out, int out_size, void* d_ws, size_t ws_size,
                              hipStream_t stream) {
    (void)in_sizes; (void)n_in; (void)out_size; (void)ws_size;
    const float* graph = (const float*)d_in[0];
    const float* capacity = (const float*)d_in[1];
    const float* sols_mask = (const float*)d_in[2];
    const float* ninf_mask = (const float*)d_in[3];
    const float* enc = (const float*)d_in[4];
    const float* Wq  = (const float*)d_in[5];
    const float* Wk  = (const float*)d_in[6];
    const float* Wv  = (const float*)d_in[7];
    const float* Wc  = (const float*)d_in[8];
    const float* bc  = (const float*)d_in[9];
    const float* Wkl = (const float*)d_in[10];
    float* out = (float*)d_out;

    // ws layout (bytes), total 94,765,056 (R4-proven)
    char* wsb = (char*)d_ws;
    short* kf_il  = (short*)(wsb);                   // 39,845,888
    short* sf8_hi = (short*)(wsb + 39845888);        // 13,631,488
    short* sf8_lo = (short*)(wsb + 53477376);        // 13,631,488
    short* wf8_hi = (short*)(wsb + 67108864);        //    131,072
    short* wf8_lo = (short*)(wsb + 67239936);        //    131,072
    float* qb     = (float*)(wsb + 67371008);        //    131,072
    float* outws  = (float*)(wsb + 67502080);        // 27,262,976 -> 94,765,056
    // v fragments live in d_out (dead before attn2 overwrites it): 39.8MB <= 40.96MB
    short* vf_il  = (short*)d_out;

    wfrag_kernel<<<dim3(4, 8), 64, 0, stream>>>(Wk, Wv, Wkl, Wc, wf8_hi, wf8_lo);
    qbase_kernel<<<B_, 128, 0, stream>>>(graph, Wq, qb);
    proj_kernel<<<MT_*B_, 64, 0, stream>>>(enc, wf8_hi, wf8_lo, kf_il, vf_il, sf8_hi, sf8_lo);
    attn1_kernel<<<NT_*B_, 256, 0, stream>>>(capacity, sols_mask, ninf_mask, Wq, qb,
                                             kf_il, vf_il, outws);
    attn2_kernel<<<NT_*B_, 64, 0, stream>>>(ninf_mask, sf8_hi, sf8_lo, wf8_hi, wf8_lo,
                                            bc, outws, out);
}